// Round 4
// baseline (98.107 us; speedup 1.0000x reference)
//
#include <hip/hip_runtime.h>
#include <math.h>

// ---- constants from the reference ----
#define ALPHA_F   0.02f
#define BETA_F    0.015f
#define E_EX_F    0.1f
#define ZEEMAN_F  (5.79e-05f * 2.0f * 0.1f)
#define SCALE_F   ((float)(1e-11 / 6.582e-16))   // T_EVO/HBAR ~= 15193.56
#define DEPH_F    1e-4f                          // DEPH*T_EVO = 1e7*1e-11

// Fused kernel: physics + block partials + last-block final reduction.
// 2 elements per thread at coalesced offsets (t, t+256) within the block chunk.
__global__ __launch_bounds__(256) void fused_k(
    const float* __restrict__ inp,   // (B,16)
    const float* __restrict__ sre,   // (B,2)
    const float* __restrict__ sim,   // (B,2)
    const float* __restrict__ exf,   // (Dex,3)
    const float* __restrict__ gap,   // (1,)
    float* __restrict__ out, long long out_size,
    unsigned* __restrict__ cnt,
    double* __restrict__ blkB, double* __restrict__ blkD,
    float2* __restrict__ firstS, float2* __restrict__ lastS,
    long long B, int Dex)
{
    const int t = threadIdx.x;
    const int nblk = gridDim.x;
    const long long base = (long long)blockIdx.x * 512;
    const long long i0 = base + t;
    const long long i1 = base + 256 + t;

    // ---- issue all global loads up-front (6 independent loads -> MLP) ----
    const float2 k0 = *reinterpret_cast<const float2*>(inp + i0 * 16);
    const float2 k1 = *reinterpret_cast<const float2*>(inp + i1 * 16);
    const float2 re0v = *reinterpret_cast<const float2*>(sre + i0 * 2);
    const float2 re1v = *reinterpret_cast<const float2*>(sre + i1 * 2);
    const float2 im0v = *reinterpret_cast<const float2*>(sim + i0 * 2);
    const float2 im1v = *reinterpret_cast<const float2*>(sim + i1 * 2);

    // uniform constants (L2-cached, wave-uniform)
    float j0 = 0.f, j1 = 0.f, j2 = 0.f;
    for (int d = 0; d < Dex; ++d) { j0 += exf[d*3]; j1 += exf[d*3+1]; j2 += exf[d*3+2]; }
    const float invD = 1.f / (float)Dex;
    const float cx  = E_EX_F * (j0 * invD);
    const float cy  = E_EX_F * (j1 * invD);
    const float hzc = E_EX_F * (j2 * invD) + ZEEMAN_F + gap[0];
    const float Ef  = expf(-SCALE_F * DEPH_F);     // exp(damp)

    const long long psi_off = 3 * B;
    const long long mom_off = 7 * B;

    __shared__ float2 sZ[512];      // (sx,sy) for the block's 512 elements
    double v1 = 0.0, v2 = 0.0;
    float zx[2], zy[2];

    const float2 kks[2]  = {k0, k1};
    const float2 res[2]  = {re0v, re1v};
    const float2 ims[2]  = {im0v, im1v};
    const long long idx[2] = {i0, i1};

    #pragma unroll
    for (int j = 0; j < 2; ++j) {
        const float2 k = kks[j];
        // normalize spinor
        const float nrm = res[j].x*res[j].x + res[j].y*res[j].y
                        + ims[j].x*ims[j].x + ims[j].y*ims[j].y;
        const float inv = rsqrtf(nrm);
        const float a0r = res[j].x*inv, a0i = ims[j].x*inv;
        const float a1r = res[j].y*inv, a1i = ims[j].y*inv;

        // effective field
        const float hx = ALPHA_F*k.y + BETA_F*k.x + cx;
        const float hy = -ALPHA_F*k.x - BETA_F*k.y + cy;

        // closed-form U = exp(damp)*[cos th  - i sin th (h.sigma)/|h|]
        const float r = sqrtf(hx*hx + hy*hy + hzc*hzc);
        float s, c;
        __sincosf(SCALE_F * r, &s, &c);
        const float f  = Ef * s / fmaxf(r, 1e-37f);
        const float Ec = Ef * c;
        const float fz = f*hzc, fx = f*hx, fy = f*hy;

        const float p0r = Ec*a0r + fz*a0i - fy*a1r + fx*a1i;
        const float p0i = Ec*a0i - fz*a0r - fy*a1i - fx*a1r;
        const float p1r = Ec*a1r - fz*a1i + fy*a0r + fx*a0i;
        const float p1i = Ec*a1i + fz*a1r + fy*a0i - fx*a0r;

        // observables
        const float crr = p0r*p1r + p0i*p1i;     // Re(p0*conj(p1))
        const float cri = p0i*p1r - p0r*p1i;     // Im(p0*conj(p1))
        const float sx = 2.f*crr, sy = 2.f*cri;
        const float sz = (p0r*p0r + p0i*p0i) - (p1r*p1r + p1i*p1i);

        const long long i = idx[j];

        // coalesced stores
        const long long o3 = i * 3;
        if (o3 + 2 < out_size) {
            out[o3 + 0] = sx; out[o3 + 1] = sy; out[o3 + 2] = sz;
        }
        const long long o4 = psi_off + i * 4;
        if (o4 + 3 < out_size)
            *reinterpret_cast<float4*>(out + o4) = make_float4(p0r, p0i, p1r, p1i);
        const long long o2 = mom_off + i * 2;
        if (o2 + 1 < out_size)
            *reinterpret_cast<float2*>(out + o2) = make_float2(k.x, k.y);

        v1 += (double)(atan2f(p1i, p1r) - atan2f(p0i, p0r));

        zx[j] = sx; zy[j] = sy;
        sZ[j * 256 + t] = make_float2(sx, sy);
    }
    __syncthreads();

    // winding diffs: wrap_pi(ang[i+1]-ang[i]) == atan2(cross, dot)
    #pragma unroll
    for (int j = 0; j < 2; ++j) {
        const int p = j * 256 + t;          // pair (p, p+1)
        if (p < 511) {
            const float2 nz = sZ[p + 1];
            const float dot = nz.x*zx[j] + nz.y*zy[j];
            const float crs = nz.y*zx[j] - nz.x*zy[j];
            v2 += (double)atan2f(crs, dot);
        }
    }
    if (t == 0)   firstS[blockIdx.x] = sZ[0];
    if (t == 255) lastS[blockIdx.x]  = make_float2(zx[1], zy[1]);

    // deterministic block tree reduction of (v1,v2)
    for (int o = 32; o; o >>= 1) { v1 += __shfl_down(v1, o); v2 += __shfl_down(v2, o); }
    __shared__ double rr1[4], rr2[4];
    __shared__ int sLast;
    const int wid = t >> 6, lane = t & 63;
    if (lane == 0) { rr1[wid] = v1; rr2[wid] = v2; }
    __syncthreads();
    if (t == 0) {
        blkB[blockIdx.x] = rr1[0] + rr1[1] + rr1[2] + rr1[3];
        blkD[blockIdx.x] = rr2[0] + rr2[1] + rr2[2] + rr2[3];
        __threadfence();                       // release partials (device scope)
        const unsigned tk = atomicAdd(cnt, 1u);
        sLast = (tk == (unsigned)(nblk - 1));
    }
    __syncthreads();
    if (!sLast) return;
    __threadfence();                           // acquire all blocks' partials

    // ---- last block: final reduction (fixed-order tree, deterministic) ----
    double s1 = 0.0, s2 = 0.0;
    for (int b = t; b < nblk; b += 256) { s1 += blkB[b]; s2 += blkD[b]; }
    for (int b = t; b < nblk - 1; b += 256) {
        const float2 a = lastS[b], f2 = firstS[b + 1];
        const float dot = f2.x*a.x + f2.y*a.y;
        const float crs = f2.y*a.x - f2.x*a.y;
        s2 += (double)atan2f(crs, dot);
    }
    for (int o = 32; o; o >>= 1) { s1 += __shfl_down(s1, o); s2 += __shfl_down(s2, o); }
    if (lane == 0) { rr1[wid] = s1; rr2[wid] = s2; }
    __syncthreads();
    if (t == 0 && out_size >= 2) {
        const double sum_dph  = rr1[0] + rr1[1] + rr1[2] + rr1[3];
        const double sum_dang = rr2[0] + rr2[1] + rr2[2] + rr2[3];
        double bp = sum_dph / (double)B;
        double w = fmod(bp + (double)M_PI, 2.0 * (double)M_PI);
        if (w < 0.0) w += 2.0 * (double)M_PI;
        out[out_size - 2] = (float)(w - (double)M_PI);                          // berry_phase
        out[out_size - 1] = (float)nearbyint(sum_dang / (2.0 * (double)M_PI)); // charge
    }
}

extern "C" void kernel_launch(void* const* d_in, const int* in_sizes, int n_in,
                              void* d_out, int out_size, void* d_ws, size_t ws_size,
                              hipStream_t stream) {
    (void)n_in; (void)ws_size;
    const float* inp = (const float*)d_in[0];
    const float* sre = (const float*)d_in[1];
    const float* sim = (const float*)d_in[2];
    const float* exf = (const float*)d_in[3];
    const float* gap = (const float*)d_in[4];

    const long long B   = (long long)in_sizes[0] / 16;   // 1048576
    const int       Dex = in_sizes[3] / 3;               // 16
    const int nblk = (int)(B / 512);                     // 2048 blocks, 2 elem/thread

    // ws layout: [0,4) counter | 64.. blkB | blkD | firstS | lastS  (~66 KB)
    char* ws = (char*)d_ws;
    unsigned* cnt   = (unsigned*)ws;
    double*  blkB   = (double*)(ws + 64);
    double*  blkD   = (double*)(ws + 64 + (size_t)nblk * 8);
    float2*  firstS = (float2*)(ws + 64 + (size_t)nblk * 16);
    float2*  lastS  = (float2*)(ws + 64 + (size_t)nblk * 24);

    hipMemsetAsync(cnt, 0, 4, stream);   // graph-capturable memset node
    fused_k<<<nblk, 256, 0, stream>>>(inp, sre, sim, exf, gap,
                                      (float*)d_out, (long long)out_size,
                                      cnt, blkB, blkD, firstS, lastS, B, Dex);
}

// Round 5
// 36.796 us; speedup vs baseline: 2.6663x; 2.6663x over previous
//
#include <hip/hip_runtime.h>
#include <math.h>

// ---- constants from the reference ----
#define ALPHA_F   0.02f
#define BETA_F    0.015f
#define E_EX_F    0.1f
#define ZEEMAN_F  (5.79e-05f * 2.0f * 0.1f)
#define SCALE_F   ((float)(1e-11 / 6.582e-16))   // T_EVO/HBAR ~= 15193.56
#define DEPH_F    1e-4f                          // DEPH*T_EVO = 1e7*1e-11
#define PI_F      3.14159265358979323846f
#define TWO_PI_F  6.28318530717958647692f

// ---- main kernel: physics + per-block partials (NO device-scope fences) ----
__global__ __launch_bounds__(256) void main_k(
    const float* __restrict__ inp,   // (B,16)
    const float* __restrict__ sre,   // (B,2)
    const float* __restrict__ sim,   // (B,2)
    const float* __restrict__ exf,   // (Dex,3)
    const float* __restrict__ gap,   // (1,)
    float* __restrict__ out, long long out_size,
    double* __restrict__ blkB, double* __restrict__ blkD,
    float2* __restrict__ firstS, float2* __restrict__ lastS,
    int chunk, long long B, int Dex)
{
    const int t = threadIdx.x;

    // uniform constants (uniform addresses -> scalar loads, L2-cached)
    float j0 = 0.f, j1 = 0.f, j2 = 0.f;
    for (int d = 0; d < Dex; ++d) { j0 += exf[d*3]; j1 += exf[d*3+1]; j2 += exf[d*3+2]; }
    const float invD = 1.f / (float)Dex;
    const float cx  = E_EX_F * (j0 * invD);
    const float cy  = E_EX_F * (j1 * invD);
    const float hzc = E_EX_F * (j2 * invD) + ZEEMAN_F + gap[0];
    const float Ef  = expf(-SCALE_F * DEPH_F);     // exp(damp)

    const long long psi_off = 3 * B;
    const long long mom_off = 7 * B;

    const long long base = (long long)blockIdx.x * chunk;
    const int ntile = chunk >> 8;

    __shared__ float2 sZ[256];       // this tile's (sx,sy)
    __shared__ float2 sCarry;        // last element's (sx,sy) of previous tile

    double v1 = 0.0, v2 = 0.0;
    float2 z = make_float2(0.f, 0.f);

    for (int tile = 0; tile < ntile; ++tile) {
        const long long i = base + (long long)tile * 256 + t;

        const float2 k  = *reinterpret_cast<const float2*>(inp + i * 16);
        const float2 re = *reinterpret_cast<const float2*>(sre + i * 2);
        const float2 im = *reinterpret_cast<const float2*>(sim + i * 2);

        // normalize spinor
        const float nrm = re.x*re.x + re.y*re.y + im.x*im.x + im.y*im.y;
        const float inv = rsqrtf(nrm);
        const float a0r = re.x*inv, a0i = im.x*inv;
        const float a1r = re.y*inv, a1i = im.y*inv;

        // effective field
        const float hx = ALPHA_F*k.y + BETA_F*k.x + cx;
        const float hy = -ALPHA_F*k.x - BETA_F*k.y + cy;

        // closed-form U = exp(damp)*[cos th - i sin th (h.sigma)/|h|]
        const float r = sqrtf(hx*hx + hy*hy + hzc*hzc);
        float s, c;
        __sincosf(SCALE_F * r, &s, &c);
        const float f  = Ef * s / fmaxf(r, 1e-37f);
        const float Ec = Ef * c;
        const float fz = f*hzc, fx = f*hx, fy = f*hy;

        const float p0r = Ec*a0r + fz*a0i - fy*a1r + fx*a1i;
        const float p0i = Ec*a0i - fz*a0r - fy*a1i - fx*a1r;
        const float p1r = Ec*a1r - fz*a1i + fy*a0r + fx*a0i;
        const float p1i = Ec*a1i + fz*a1r + fy*a0i - fx*a0r;

        // observables
        const float crr = p0r*p1r + p0i*p1i;     // Re(p0*conj(p1))
        const float cri = p0i*p1r - p0r*p1i;     // Im(p0*conj(p1))
        const float sx = 2.f*crr, sy = 2.f*cri;
        const float sz = (p0r*p0r + p0i*p0i) - (p1r*p1r + p1i*p1i);

        // coalesced stores (guarded)
        const long long o3 = i * 3;
        if (o3 + 2 < out_size) {
            out[o3 + 0] = sx; out[o3 + 1] = sy; out[o3 + 2] = sz;
        }
        const long long o4 = psi_off + i * 4;
        if (o4 + 3 < out_size)
            *reinterpret_cast<float4*>(out + o4) = make_float4(p0r, p0i, p1r, p1i);
        const long long o2 = mom_off + i * 2;
        if (o2 + 1 < out_size)
            *reinterpret_cast<float2*>(out + o2) = make_float2(k.x, k.y);

        v1 += (double)(atan2f(p1i, p1r) - atan2f(p0i, p0r));

        sZ[t] = make_float2(sx, sy);
        __syncthreads();

        // winding diffs: wrap_pi(ang[i+1]-ang[i]) == atan2(cross, dot)
        if (t < 255) {
            const float2 nz = sZ[t + 1];
            const float dot = nz.x*sx + nz.y*sy;
            const float crs = nz.y*sx - nz.x*sy;
            v2 += (double)atan2f(crs, dot);
        }
        if (t == 0 && tile > 0) {
            const float2 pz = sCarry;       // prev tile's last element
            const float2 cz = sZ[0];
            const float dot = cz.x*pz.x + cz.y*pz.y;
            const float crs = cz.y*pz.x - cz.x*pz.y;
            v2 += (double)atan2f(crs, dot);
        }
        if (t == 0 && tile == 0) firstS[blockIdx.x] = sZ[0];

        z = make_float2(sx, sy);
        __syncthreads();
        if (t == 255) sCarry = z;
    }
    if (t == 255) lastS[blockIdx.x] = z;

    // deterministic block tree reduction of (v1,v2)
    for (int o = 32; o; o >>= 1) { v1 += __shfl_down(v1, o); v2 += __shfl_down(v2, o); }
    __shared__ double rr1[4], rr2[4];
    const int wid = t >> 6, lane = t & 63;
    if (lane == 0) { rr1[wid] = v1; rr2[wid] = v2; }
    __syncthreads();
    if (t == 0) {
        blkB[blockIdx.x] = rr1[0] + rr1[1] + rr1[2] + rr1[3];
        blkD[blockIdx.x] = rr2[0] + rr2[1] + rr2[2] + rr2[3];
    }
}

// ---- final scalar reduction (separate kernel: implicit full visibility) ----
__global__ __launch_bounds__(256) void final_k(
    const double* __restrict__ blkB, const double* __restrict__ blkD,
    const float2* __restrict__ firstS, const float2* __restrict__ lastS,
    int nblk, long long B, float* __restrict__ out, long long out_size)
{
    const int t = threadIdx.x;
    double s1 = 0.0, s2 = 0.0;
    for (int b = t; b < nblk; b += 256) { s1 += blkB[b]; s2 += blkD[b]; }
    for (int b = t; b < nblk - 1; b += 256) {
        const float2 a = lastS[b], f2 = firstS[b + 1];
        const float dot = f2.x*a.x + f2.y*a.y;
        const float crs = f2.y*a.x - f2.x*a.y;
        s2 += (double)atan2f(crs, dot);
    }
    for (int o = 32; o; o >>= 1) { s1 += __shfl_down(s1, o); s2 += __shfl_down(s2, o); }
    __shared__ double rr1[4], rr2[4];
    const int wid = t >> 6, lane = t & 63;
    if (lane == 0) { rr1[wid] = s1; rr2[wid] = s2; }
    __syncthreads();
    if (t == 0 && out_size >= 2) {
        const double sum_dph  = rr1[0] + rr1[1] + rr1[2] + rr1[3];
        const double sum_dang = rr2[0] + rr2[1] + rr2[2] + rr2[3];
        double bp = sum_dph / (double)B;
        double w = fmod(bp + (double)M_PI, 2.0 * (double)M_PI);
        if (w < 0.0) w += 2.0 * (double)M_PI;
        out[out_size - 2] = (float)(w - (double)M_PI);                          // berry_phase
        out[out_size - 1] = (float)nearbyint(sum_dang / (2.0 * (double)M_PI)); // charge
    }
}

extern "C" void kernel_launch(void* const* d_in, const int* in_sizes, int n_in,
                              void* d_out, int out_size, void* d_ws, size_t ws_size,
                              hipStream_t stream) {
    (void)n_in;
    const float* inp = (const float*)d_in[0];
    const float* sre = (const float*)d_in[1];
    const float* sim = (const float*)d_in[2];
    const float* exf = (const float*)d_in[3];
    const float* gap = (const float*)d_in[4];

    const long long B   = (long long)in_sizes[0] / 16;   // 1048576
    const int       Dex = in_sizes[3] / 3;               // 16

    // largest block count whose ws partials fit: 24 B/block (+pad)
    int nblk = 64;
    const int cands[7] = {4096, 2048, 1024, 512, 256, 128, 64};
    for (int ci = 0; ci < 7; ++ci) {
        const int c = cands[ci];
        if (B % ((long long)c * 256) == 0 && (size_t)c * 24 + 64 <= ws_size) {
            nblk = c;
            break;
        }
    }
    const int chunk = (int)(B / nblk);   // multiple of 256

    char* ws = (char*)d_ws;
    double*  blkB   = (double*)(ws);
    double*  blkD   = (double*)(ws + (size_t)nblk * 8);
    float2*  firstS = (float2*)(ws + (size_t)nblk * 16);
    float2*  lastS  = (float2*)(ws + (size_t)nblk * 24 - (size_t)nblk * 8); // = ws + nblk*16 + nblk*8
    // fix explicit layout (no overlap): blkB[nblk], blkD[nblk], firstS[nblk], lastS[nblk]
    blkB   = (double*)(ws);
    blkD   = (double*)(ws + (size_t)nblk * 8);
    firstS = (float2*)(ws + (size_t)nblk * 16);
    lastS  = (float2*)(ws + (size_t)nblk * 16 + (size_t)nblk * 8);

    main_k<<<nblk, 256, 0, stream>>>(inp, sre, sim, exf, gap,
                                     (float*)d_out, (long long)out_size,
                                     blkB, blkD, firstS, lastS,
                                     chunk, B, Dex);
    final_k<<<1, 256, 0, stream>>>(blkB, blkD, firstS, lastS,
                                   nblk, B, (float*)d_out, (long long)out_size);
}

// Round 6
// 32.583 us; speedup vs baseline: 3.0110x; 1.1293x over previous
//
#include <hip/hip_runtime.h>
#include <math.h>

// ---- constants from the reference ----
#define ALPHA_F   0.02f
#define BETA_F    0.015f
#define E_EX_F    0.1f
#define ZEEMAN_F  (5.79e-05f * 2.0f * 0.1f)
#define SCALE_F   ((float)(1e-11 / 6.582e-16))   // T_EVO/HBAR ~= 15193.56
#define DEPH_F    1e-4f                          // DEPH*T_EVO = 1e7*1e-11

// ---- main kernel: physics + per-block partials (no device-scope fences) ----
__global__ __launch_bounds__(256) void main_k(
    const float* __restrict__ inp,   // (B,16)
    const float* __restrict__ sre,   // (B,2)
    const float* __restrict__ sim,   // (B,2)
    const float* __restrict__ exf,   // (Dex,3)
    const float* __restrict__ gap,   // (1,)
    float* __restrict__ out, long long out_size,
    double* __restrict__ blkB, double* __restrict__ blkD,
    float2* __restrict__ firstS, float2* __restrict__ lastS,
    int chunk, long long B, int Dex)
{
    const int t = threadIdx.x;
    const long long base = (long long)blockIdx.x * chunk;
    const int ntile = chunk >> 8;

    // issue first tile's loads immediately (before uniform-constant work)
    float2 k_c  = *reinterpret_cast<const float2*>(inp + (base + t) * 16);
    float2 re_c = *reinterpret_cast<const float2*>(sre + (base + t) * 2);
    float2 im_c = *reinterpret_cast<const float2*>(sim + (base + t) * 2);

    // uniform constants (uniform addresses -> scalar loads, L2-cached)
    float j0 = 0.f, j1 = 0.f, j2 = 0.f;
    for (int d = 0; d < Dex; ++d) { j0 += exf[d*3]; j1 += exf[d*3+1]; j2 += exf[d*3+2]; }
    const float invD = 1.f / (float)Dex;
    const float cx  = E_EX_F * (j0 * invD);
    const float cy  = E_EX_F * (j1 * invD);
    const float hzc = E_EX_F * (j2 * invD) + ZEEMAN_F + gap[0];
    const float Ef  = expf(-SCALE_F * DEPH_F);     // exp(damp)

    const long long psi_off = 3 * B;
    const long long mom_off = 7 * B;

    __shared__ float  sS[768];       // staged sx,sy,sz for dense stores
    __shared__ float2 sFirst[4];     // lane-0 z of each wave (wave-boundary pairs)
    __shared__ float2 sCarry[2];     // t==255 z, double-buffered across tiles
    __shared__ double rr1[4], rr2[4];

    double v1 = 0.0, v2 = 0.0;
    float2 zlast = make_float2(0.f, 0.f);
    const int wid = t >> 6, lane = t & 63;

    for (int tile = 0; tile < ntile; ++tile) {
        const long long icur = base + (long long)tile * 256 + t;
        const float2 k = k_c, re = re_c, im = im_c;

        // prefetch next tile (keeps 3 more loads in flight during compute)
        if (tile + 1 < ntile) {
            const long long inx = icur + 256;
            k_c  = *reinterpret_cast<const float2*>(inp + inx * 16);
            re_c = *reinterpret_cast<const float2*>(sre + inx * 2);
            im_c = *reinterpret_cast<const float2*>(sim + inx * 2);
        }

        // normalize spinor
        const float nrm = re.x*re.x + re.y*re.y + im.x*im.x + im.y*im.y;
        const float inv = rsqrtf(nrm);
        const float a0r = re.x*inv, a0i = im.x*inv;
        const float a1r = re.y*inv, a1i = im.y*inv;

        // effective field
        const float hx = ALPHA_F*k.y + BETA_F*k.x + cx;
        const float hy = -ALPHA_F*k.x - BETA_F*k.y + cy;

        // closed-form U = exp(damp)*[cos th - i sin th (h.sigma)/|h|]
        const float r = sqrtf(hx*hx + hy*hy + hzc*hzc);
        float s, c;
        __sincosf(SCALE_F * r, &s, &c);
        const float f  = Ef * s / fmaxf(r, 1e-37f);
        const float Ec = Ef * c;
        const float fz = f*hzc, fx = f*hx, fy = f*hy;

        const float p0r = Ec*a0r + fz*a0i - fy*a1r + fx*a1i;
        const float p0i = Ec*a0i - fz*a0r - fy*a1i - fx*a1r;
        const float p1r = Ec*a1r - fz*a1i + fy*a0r + fx*a0i;
        const float p1i = Ec*a1i + fz*a1r + fy*a0i - fx*a0r;

        // observables
        const float crr = p0r*p1r + p0i*p1i;     // Re(p0*conj(p1))
        const float cri = p0i*p1r - p0r*p1i;     // Im(p0*conj(p1))
        const float sx = 2.f*crr, sy = 2.f*cri;
        const float sz = (p0r*p0r + p0i*p0i) - (p1r*p1r + p1i*p1i);

        // dense stores: psi (float4/lane), momentum (float2/lane)
        const long long o4 = psi_off + icur * 4;
        if (o4 + 3 < out_size)
            *reinterpret_cast<float4*>(out + o4) = make_float4(p0r, p0i, p1r, p1i);
        const long long o2 = mom_off + icur * 2;
        if (o2 + 1 < out_size)
            *reinterpret_cast<float2*>(out + o2) = make_float2(k.x, k.y);

        // stage spin triple for dense full-line stores (stride-3: gcd(3,32)=1, conflict-free)
        sS[t*3 + 0] = sx; sS[t*3 + 1] = sy; sS[t*3 + 2] = sz;
        if (lane == 0)  sFirst[wid] = make_float2(sx, sy);
        if (t == 255)   sCarry[tile & 1] = make_float2(sx, sy);

        // in-wave neighbor via shuffle
        const float znx = __shfl_down(sx, 1);
        const float zny = __shfl_down(sy, 1);
        __syncthreads();

        // out_s: three dense wave-segments (full 64B lines)
        const long long tb3 = (base + (long long)tile * 256) * 3;
        if (tb3 + 767 < out_size) {
            out[tb3 + t]       = sS[t];
            out[tb3 + 256 + t] = sS[256 + t];
            out[tb3 + 512 + t] = sS[512 + t];
        } else {
            if (tb3 + t < out_size)       out[tb3 + t]       = sS[t];
            if (tb3 + 256 + t < out_size) out[tb3 + 256 + t] = sS[256 + t];
            if (tb3 + 512 + t < out_size) out[tb3 + 512 + t] = sS[512 + t];
        }

        // berry phase term
        v1 += (double)(atan2f(p1i, p1r) - atan2f(p0i, p0r));

        // winding diffs: wrap_pi(ang[i+1]-ang[i]) == atan2(cross(cur,next), dot)
        if (lane < 63) {
            const float dot = znx*sx + zny*sy;
            const float crs = sx*zny - sy*znx;
            v2 += (double)atan2f(crs, dot);
        } else if (wid < 3) {
            const float2 nf = sFirst[wid + 1];
            const float dot = nf.x*sx + nf.y*sy;
            const float crs = sx*nf.y - sy*nf.x;
            v2 += (double)atan2f(crs, dot);
        }
        if (t == 0) {
            if (tile > 0) {
                const float2 pz = sCarry[(tile & 1) ^ 1];   // prev tile's last
                const float dot = sx*pz.x + sy*pz.y;
                const float crs = pz.x*sy - pz.y*sx;        // cross(prev, cur)
                v2 += (double)atan2f(crs, dot);
            } else {
                firstS[blockIdx.x] = make_float2(sx, sy);
            }
        }
        if (t == 255) zlast = make_float2(sx, sy);
        __syncthreads();   // protect sS/sFirst reuse next tile
    }
    if (t == 255) lastS[blockIdx.x] = zlast;

    // deterministic block tree reduction of (v1,v2)
    for (int o = 32; o; o >>= 1) { v1 += __shfl_down(v1, o); v2 += __shfl_down(v2, o); }
    if (lane == 0) { rr1[wid] = v1; rr2[wid] = v2; }
    __syncthreads();
    if (t == 0) {
        blkB[blockIdx.x] = rr1[0] + rr1[1] + rr1[2] + rr1[3];
        blkD[blockIdx.x] = rr2[0] + rr2[1] + rr2[2] + rr2[3];
    }
}

// ---- final scalar reduction (separate kernel: implicit full visibility) ----
__global__ __launch_bounds__(256) void final_k(
    const double* __restrict__ blkB, const double* __restrict__ blkD,
    const float2* __restrict__ firstS, const float2* __restrict__ lastS,
    int nblk, long long B, float* __restrict__ out, long long out_size)
{
    const int t = threadIdx.x;
    double s1 = 0.0, s2 = 0.0;
    for (int b = t; b < nblk; b += 256) { s1 += blkB[b]; s2 += blkD[b]; }
    for (int b = t; b < nblk - 1; b += 256) {
        const float2 a = lastS[b], f2 = firstS[b + 1];
        const float dot = f2.x*a.x + f2.y*a.y;
        const float crs = a.x*f2.y - a.y*f2.x;              // cross(prev, cur)
        s2 += (double)atan2f(crs, dot);
    }
    for (int o = 32; o; o >>= 1) { s1 += __shfl_down(s1, o); s2 += __shfl_down(s2, o); }
    __shared__ double rr1[4], rr2[4];
    const int wid = t >> 6, lane = t & 63;
    if (lane == 0) { rr1[wid] = s1; rr2[wid] = s2; }
    __syncthreads();
    if (t == 0 && out_size >= 2) {
        const double sum_dph  = rr1[0] + rr1[1] + rr1[2] + rr1[3];
        const double sum_dang = rr2[0] + rr2[1] + rr2[2] + rr2[3];
        double bp = sum_dph / (double)B;
        double w = fmod(bp + (double)M_PI, 2.0 * (double)M_PI);
        if (w < 0.0) w += 2.0 * (double)M_PI;
        out[out_size - 2] = (float)(w - (double)M_PI);                          // berry_phase
        out[out_size - 1] = (float)nearbyint(sum_dang / (2.0 * (double)M_PI)); // charge
    }
}

extern "C" void kernel_launch(void* const* d_in, const int* in_sizes, int n_in,
                              void* d_out, int out_size, void* d_ws, size_t ws_size,
                              hipStream_t stream) {
    (void)n_in;
    const float* inp = (const float*)d_in[0];
    const float* sre = (const float*)d_in[1];
    const float* sim = (const float*)d_in[2];
    const float* exf = (const float*)d_in[3];
    const float* gap = (const float*)d_in[4];

    const long long B   = (long long)in_sizes[0] / 16;   // 1048576
    const int       Dex = in_sizes[3] / 3;               // 16

    // largest block count whose ws partials fit: 32 B/block (+pad)
    // prefer 2048 = exactly 8 blocks/CU (one full residency round)
    int nblk = 64;
    const int cands[6] = {2048, 1024, 512, 256, 128, 64};
    for (int ci = 0; ci < 6; ++ci) {
        const int c = cands[ci];
        if (B % ((long long)c * 256) == 0 && (size_t)c * 32 + 64 <= ws_size) {
            nblk = c;
            break;
        }
    }
    const int chunk = (int)(B / nblk);   // multiple of 256

    char* ws = (char*)d_ws;
    double*  blkB   = (double*)(ws);
    double*  blkD   = (double*)(ws + (size_t)nblk * 8);
    float2*  firstS = (float2*)(ws + (size_t)nblk * 16);
    float2*  lastS  = (float2*)(ws + (size_t)nblk * 24);

    main_k<<<nblk, 256, 0, stream>>>(inp, sre, sim, exf, gap,
                                     (float*)d_out, (long long)out_size,
                                     blkB, blkD, firstS, lastS,
                                     chunk, B, Dex);
    final_k<<<1, 256, 0, stream>>>(blkB, blkD, firstS, lastS,
                                   nblk, B, (float*)d_out, (long long)out_size);
}

// Round 7
// 30.774 us; speedup vs baseline: 3.1880x; 1.0588x over previous
//
#include <hip/hip_runtime.h>
#include <math.h>

// ---- constants from the reference ----
#define ALPHA_F   0.02f
#define BETA_F    0.015f
#define E_EX_F    0.1f
#define ZEEMAN_F  (5.79e-05f * 2.0f * 0.1f)
#define SCALE_F   ((float)(1e-11 / 6.582e-16))   // T_EVO/HBAR ~= 15193.56
#define DEPH_F    1e-4f                          // DEPH*T_EVO = 1e7*1e-11

typedef float vf2 __attribute__((ext_vector_type(2)));
typedef float vf4 __attribute__((ext_vector_type(4)));

// ---- main kernel: physics + per-block partials (no device-scope fences) ----
__global__ __launch_bounds__(256) void main_k(
    const float* __restrict__ inp,   // (B,16)
    const float* __restrict__ sre,   // (B,2)
    const float* __restrict__ sim,   // (B,2)
    const float* __restrict__ exf,   // (Dex,3)
    const float* __restrict__ gap,   // (1,)
    float* __restrict__ out, long long out_size,
    double* __restrict__ blkB, double* __restrict__ blkD,
    float2* __restrict__ firstS, float2* __restrict__ lastS,
    int chunk, long long B, int Dex)
{
    const int t = threadIdx.x;
    const long long base = (long long)blockIdx.x * chunk;
    const int ntile = chunk >> 8;

    // issue first tile's loads immediately (non-temporal: pure streaming, no reuse)
    vf2 k_c  = __builtin_nontemporal_load((const vf2*)(inp + (base + t) * 16));
    vf2 re_c = __builtin_nontemporal_load((const vf2*)(sre + (base + t) * 2));
    vf2 im_c = __builtin_nontemporal_load((const vf2*)(sim + (base + t) * 2));

    // uniform constants (uniform addresses -> scalar loads, L2-cached)
    float j0 = 0.f, j1 = 0.f, j2 = 0.f;
    for (int d = 0; d < Dex; ++d) { j0 += exf[d*3]; j1 += exf[d*3+1]; j2 += exf[d*3+2]; }
    const float invD = 1.f / (float)Dex;
    const float cx  = E_EX_F * (j0 * invD);
    const float cy  = E_EX_F * (j1 * invD);
    const float hzc = E_EX_F * (j2 * invD) + ZEEMAN_F + gap[0];
    const float Ef  = expf(-SCALE_F * DEPH_F);     // exp(damp)

    const long long psi_off = 3 * B;
    const long long mom_off = 7 * B;

    __shared__ float  sS[768];       // staged sx,sy,sz for dense stores
    __shared__ float2 sFirst[4];     // lane-0 z of each wave (wave-boundary pairs)
    __shared__ float2 sCarry[2];     // t==255 z, double-buffered across tiles
    __shared__ double rr1[4], rr2[4];

    double v1 = 0.0, v2 = 0.0;
    float2 zlast = make_float2(0.f, 0.f);
    const int wid = t >> 6, lane = t & 63;

    for (int tile = 0; tile < ntile; ++tile) {
        const long long icur = base + (long long)tile * 256 + t;
        const vf2 k = k_c, re = re_c, im = im_c;

        // prefetch next tile (keeps 3 more loads in flight during compute)
        if (tile + 1 < ntile) {
            const long long inx = icur + 256;
            k_c  = __builtin_nontemporal_load((const vf2*)(inp + inx * 16));
            re_c = __builtin_nontemporal_load((const vf2*)(sre + inx * 2));
            im_c = __builtin_nontemporal_load((const vf2*)(sim + inx * 2));
        }

        // normalize spinor
        const float nrm = re.x*re.x + re.y*re.y + im.x*im.x + im.y*im.y;
        const float inv = rsqrtf(nrm);
        const float a0r = re.x*inv, a0i = im.x*inv;
        const float a1r = re.y*inv, a1i = im.y*inv;

        // effective field
        const float hx = ALPHA_F*k.y + BETA_F*k.x + cx;
        const float hy = -ALPHA_F*k.x - BETA_F*k.y + cy;

        // closed-form U = exp(damp)*[cos th - i sin th (h.sigma)/|h|]
        const float r = sqrtf(hx*hx + hy*hy + hzc*hzc);
        float s, c;
        __sincosf(SCALE_F * r, &s, &c);
        const float f  = Ef * s / fmaxf(r, 1e-37f);
        const float Ec = Ef * c;
        const float fz = f*hzc, fx = f*hx, fy = f*hy;

        const float p0r = Ec*a0r + fz*a0i - fy*a1r + fx*a1i;
        const float p0i = Ec*a0i - fz*a0r - fy*a1i - fx*a1r;
        const float p1r = Ec*a1r - fz*a1i + fy*a0r + fx*a0i;
        const float p1i = Ec*a1i + fz*a1r + fy*a0i - fx*a0r;

        // observables
        const float crr = p0r*p1r + p0i*p1i;     // Re(p0*conj(p1))
        const float cri = p0i*p1r - p0r*p1i;     // Im(p0*conj(p1))
        const float sx = 2.f*crr, sy = 2.f*cri;
        const float sz = (p0r*p0r + p0i*p0i) - (p1r*p1r + p1i*p1i);

        // dense NT stores: psi (float4/lane), momentum (float2/lane)
        const long long o4 = psi_off + icur * 4;
        if (o4 + 3 < out_size) {
            vf4 pv = {p0r, p0i, p1r, p1i};
            __builtin_nontemporal_store(pv, (vf4*)(out + o4));
        }
        const long long o2 = mom_off + icur * 2;
        if (o2 + 1 < out_size) {
            vf2 mv = {k.x, k.y};
            __builtin_nontemporal_store(mv, (vf2*)(out + o2));
        }

        // stage spin triple for dense full-line stores (stride-3: gcd(3,32)=1, conflict-free)
        sS[t*3 + 0] = sx; sS[t*3 + 1] = sy; sS[t*3 + 2] = sz;
        if (lane == 0)  sFirst[wid] = make_float2(sx, sy);
        if (t == 255)   sCarry[tile & 1] = make_float2(sx, sy);

        // in-wave neighbor via shuffle
        const float znx = __shfl_down(sx, 1);
        const float zny = __shfl_down(sy, 1);
        __syncthreads();

        // out_s: three dense wave-segments (full 64B lines), non-temporal
        const long long tb3 = (base + (long long)tile * 256) * 3;
        if (tb3 + 767 < out_size) {
            __builtin_nontemporal_store(sS[t],       out + tb3 + t);
            __builtin_nontemporal_store(sS[256 + t], out + tb3 + 256 + t);
            __builtin_nontemporal_store(sS[512 + t], out + tb3 + 512 + t);
        } else {
            if (tb3 + t < out_size)       out[tb3 + t]       = sS[t];
            if (tb3 + 256 + t < out_size) out[tb3 + 256 + t] = sS[256 + t];
            if (tb3 + 512 + t < out_size) out[tb3 + 512 + t] = sS[512 + t];
        }

        // berry phase term
        v1 += (double)(atan2f(p1i, p1r) - atan2f(p0i, p0r));

        // winding diffs: wrap_pi(ang[i+1]-ang[i]) == atan2(cross(cur,next), dot)
        if (lane < 63) {
            const float dot = znx*sx + zny*sy;
            const float crs = sx*zny - sy*znx;
            v2 += (double)atan2f(crs, dot);
        } else if (wid < 3) {
            const float2 nf = sFirst[wid + 1];
            const float dot = nf.x*sx + nf.y*sy;
            const float crs = sx*nf.y - sy*nf.x;
            v2 += (double)atan2f(crs, dot);
        }
        if (t == 0) {
            if (tile > 0) {
                const float2 pz = sCarry[(tile & 1) ^ 1];   // prev tile's last
                const float dot = sx*pz.x + sy*pz.y;
                const float crs = pz.x*sy - pz.y*sx;        // cross(prev, cur)
                v2 += (double)atan2f(crs, dot);
            } else {
                firstS[blockIdx.x] = make_float2(sx, sy);
            }
        }
        if (t == 255) zlast = make_float2(sx, sy);
        __syncthreads();   // protect sS/sFirst reuse next tile
    }
    if (t == 255) lastS[blockIdx.x] = zlast;

    // deterministic block tree reduction of (v1,v2)
    for (int o = 32; o; o >>= 1) { v1 += __shfl_down(v1, o); v2 += __shfl_down(v2, o); }
    if (lane == 0) { rr1[wid] = v1; rr2[wid] = v2; }
    __syncthreads();
    if (t == 0) {
        blkB[blockIdx.x] = rr1[0] + rr1[1] + rr1[2] + rr1[3];
        blkD[blockIdx.x] = rr2[0] + rr2[1] + rr2[2] + rr2[3];
    }
}

// ---- final scalar reduction (separate kernel: implicit full visibility) ----
__global__ __launch_bounds__(256) void final_k(
    const double* __restrict__ blkB, const double* __restrict__ blkD,
    const float2* __restrict__ firstS, const float2* __restrict__ lastS,
    int nblk, long long B, float* __restrict__ out, long long out_size)
{
    const int t = threadIdx.x;
    double s1 = 0.0, s2 = 0.0;
    for (int b = t; b < nblk; b += 256) { s1 += blkB[b]; s2 += blkD[b]; }
    for (int b = t; b < nblk - 1; b += 256) {
        const float2 a = lastS[b], f2 = firstS[b + 1];
        const float dot = f2.x*a.x + f2.y*a.y;
        const float crs = a.x*f2.y - a.y*f2.x;              // cross(prev, cur)
        s2 += (double)atan2f(crs, dot);
    }
    for (int o = 32; o; o >>= 1) { s1 += __shfl_down(s1, o); s2 += __shfl_down(s2, o); }
    __shared__ double rr1[4], rr2[4];
    const int wid = t >> 6, lane = t & 63;
    if (lane == 0) { rr1[wid] = s1; rr2[wid] = s2; }
    __syncthreads();
    if (t == 0 && out_size >= 2) {
        const double sum_dph  = rr1[0] + rr1[1] + rr1[2] + rr1[3];
        const double sum_dang = rr2[0] + rr2[1] + rr2[2] + rr2[3];
        double bp = sum_dph / (double)B;
        double w = fmod(bp + (double)M_PI, 2.0 * (double)M_PI);
        if (w < 0.0) w += 2.0 * (double)M_PI;
        out[out_size - 2] = (float)(w - (double)M_PI);                          // berry_phase
        out[out_size - 1] = (float)nearbyint(sum_dang / (2.0 * (double)M_PI)); // charge
    }
}

extern "C" void kernel_launch(void* const* d_in, const int* in_sizes, int n_in,
                              void* d_out, int out_size, void* d_ws, size_t ws_size,
                              hipStream_t stream) {
    (void)n_in;
    const float* inp = (const float*)d_in[0];
    const float* sre = (const float*)d_in[1];
    const float* sim = (const float*)d_in[2];
    const float* exf = (const float*)d_in[3];
    const float* gap = (const float*)d_in[4];

    const long long B   = (long long)in_sizes[0] / 16;   // 1048576
    const int       Dex = in_sizes[3] / 3;               // 16

    // largest block count whose ws partials fit: 32 B/block (+pad)
    // prefer 2048 = exactly 8 blocks/CU (one full residency round)
    int nblk = 64;
    const int cands[6] = {2048, 1024, 512, 256, 128, 64};
    for (int ci = 0; ci < 6; ++ci) {
        const int c = cands[ci];
        if (B % ((long long)c * 256) == 0 && (size_t)c * 32 + 64 <= ws_size) {
            nblk = c;
            break;
        }
    }
    const int chunk = (int)(B / nblk);   // multiple of 256

    char* ws = (char*)d_ws;
    double*  blkB   = (double*)(ws);
    double*  blkD   = (double*)(ws + (size_t)nblk * 8);
    float2*  firstS = (float2*)(ws + (size_t)nblk * 16);
    float2*  lastS  = (float2*)(ws + (size_t)nblk * 24);

    main_k<<<nblk, 256, 0, stream>>>(inp, sre, sim, exf, gap,
                                     (float*)d_out, (long long)out_size,
                                     blkB, blkD, firstS, lastS,
                                     chunk, B, Dex);
    final_k<<<1, 256, 0, stream>>>(blkB, blkD, firstS, lastS,
                                   nblk, B, (float*)d_out, (long long)out_size);
}